// Round 26
// baseline (489.902 us; speedup 1.0000x reference)
//
#include <hip/hip_runtime.h>
#include <math.h>

typedef __bf16 bf16x8 __attribute__((ext_vector_type(8)));
typedef float f32x4 __attribute__((ext_vector_type(4)));
typedef unsigned short u16;
typedef unsigned short u16x4 __attribute__((ext_vector_type(4)));
typedef unsigned short u16x8 __attribute__((ext_vector_type(8)));
typedef unsigned int u32;

#define AS1 __attribute__((address_space(1)))
#define AS3 __attribute__((address_space(3)))

static __device__ __forceinline__ float bf2f(u16 u) {
  union { u32 i; float f; } v; v.i = ((u32)u) << 16; return v.f;
}
// native RTNE hardware convert
static __device__ __forceinline__ u16 f2bf(float f) {
  union { __bf16 b; u16 u; } v; v.b = (__bf16)f; return v.u;
}

// ---- merged fp32 -> bf16 convert for all three inputs (dst contiguous) ----
__global__ __launch_bounds__(256)
void conv_all(const float* __restrict__ x, const float* __restrict__ wq,
              const float* __restrict__ wp, u16* __restrict__ dst) {
  const int gid = blockIdx.x * 256 + threadIdx.x;  // 0..6291455 (x4 elems)
  const float* src;
  int off;
  if (gid < 2097152) { src = x; off = gid; }
  else if (gid < 2097152 + 3145728) { src = wq; off = gid - 2097152; }
  else { src = wp; off = gid - (2097152 + 3145728); }
  const float4 v = ((const float4*)src)[off];
  u16x4 p = {f2bf(v.x), f2bf(v.y), f2bf(v.z), f2bf(v.w)};
  ((u16x4*)dst)[gid] = p;
}

// ---- GEMM 128x128, BK=64 (r19-exact): m97 2-barrier structure ----
template <bool CF32>
__global__ __launch_bounds__(256, 4)
void gemm_bt(const u16* __restrict__ A, const u16* __restrict__ B,
             void* __restrict__ Cp, int M, int N, int K) {
  __shared__ __align__(16) u16 As[128 * 64];   // 16 KB
  __shared__ __align__(16) u16 Bs[128 * 64];   // 16 KB
  const int tid = threadIdx.x;
  const int lane = tid & 63;
  const int wid = tid >> 6;
  const int wr = wid >> 1, wc = wid & 1;
  const int l15 = lane & 15, l4 = lane >> 4;
  const int m0 = blockIdx.y * 128, n0 = blockIdx.x * 128;

  int grow[4], gkc[4];
#pragma unroll
  for (int i = 0; i < 4; ++i) {
    const int idx = i * 256 + tid;
    grow[i] = idx >> 3;
    gkc[i] = ((idx & 7) ^ (grow[i] & 7)) * 8;
  }

  const f32x4 fzero = {0.f, 0.f, 0.f, 0.f};
  f32x4 acc[4][4];
#pragma unroll
  for (int i = 0; i < 4; ++i)
#pragma unroll
    for (int j = 0; j < 4; ++j) acc[i][j] = fzero;

  for (int kt = 0; kt < K; kt += 64) {
#pragma unroll
    for (int i = 0; i < 4; ++i) {
      __builtin_amdgcn_global_load_lds(
          (AS1 void*)(A + (size_t)(m0 + grow[i]) * K + kt + gkc[i]),
          (AS3 void*)(As + (size_t)(i * 256 + tid) * 8), 16, 0, 0);
      __builtin_amdgcn_global_load_lds(
          (AS1 void*)(B + (size_t)(n0 + grow[i]) * K + kt + gkc[i]),
          (AS3 void*)(Bs + (size_t)(i * 256 + tid) * 8), 16, 0, 0);
    }
    __syncthreads();
    bf16x8 af[4][2], bfr[4][2];
#pragma unroll
    for (int m = 0; m < 4; ++m) {
      const int ra = wr * 64 + m * 16 + l15;
#pragma unroll
      for (int ks = 0; ks < 2; ++ks)
        af[m][ks] = *(const bf16x8*)&As[ra * 64 + (((ks * 4 + l4) ^ (ra & 7)) << 3)];
    }
#pragma unroll
    for (int n = 0; n < 4; ++n) {
      const int rb = wc * 64 + n * 16 + l15;
#pragma unroll
      for (int ks = 0; ks < 2; ++ks)
        bfr[n][ks] = *(const bf16x8*)&Bs[rb * 64 + (((ks * 4 + l4) ^ (rb & 7)) << 3)];
    }
    __builtin_amdgcn_s_setprio(1);
#pragma unroll
    for (int m = 0; m < 4; ++m)
#pragma unroll
      for (int n = 0; n < 4; ++n) {
        acc[m][n] = __builtin_amdgcn_mfma_f32_16x16x32_bf16(af[m][0], bfr[n][0], acc[m][n], 0, 0, 0);
        acc[m][n] = __builtin_amdgcn_mfma_f32_16x16x32_bf16(af[m][1], bfr[n][1], acc[m][n], 0, 0, 0);
      }
    __builtin_amdgcn_s_setprio(0);
    __syncthreads();
  }

#pragma unroll
  for (int m = 0; m < 4; ++m)
#pragma unroll
    for (int r = 0; r < 4; ++r) {
      const int gm = m0 + wr * 64 + m * 16 + l4 * 4 + r;
      if constexpr (CF32) {
        float* crow = (float*)Cp + (size_t)gm * N + n0 + wc * 64 + l15;
#pragma unroll
        for (int n = 0; n < 4; ++n) crow[n * 16] = acc[m][n][r];
      } else {
        u16* crow = (u16*)Cp + (size_t)gm * N + n0 + wc * 64 + l15;
#pragma unroll
        for (int n = 0; n < 4; ++n) crow[n * 16] = f2bf(acc[m][n][r]);
      }
    }
}

// ---- prep: RoPE on Q,K (blocks 0..2047) + V transpose (blocks 2048..4095) ----
// The two halves touch disjoint regions of qkv (Q,K vs V) -> independent.
__global__ __launch_bounds__(256)
void prep_kernel(u16* __restrict__ qkv, u16* __restrict__ vT,
                 const int* __restrict__ seq_off) {
  __shared__ __align__(16) u16 tile[64][72];
  const int blk = blockIdx.x;
  const int tid = threadIdx.x;
  if (blk < 2048) {
    // ---- RoPE (r19-exact logic) ----
    const int idx = blk * 256 + tid;
    const int d8 = idx & 7;
    const int h = (idx >> 3) & 15;
    const int t = (idx >> 7) & 2047;
    const int b = idx >> 18;
    const int d0 = d8 * 8;
    const float pos = (float)(seq_off[0] + t);
    const size_t base = ((size_t)(b * 2048 + t)) * 6144 + h * 128 + d0;
    const u16x8 qlo = *(const u16x8*)(qkv + base);
    const u16x8 qhi = *(const u16x8*)(qkv + base + 64);
    const u16x8 klo = *(const u16x8*)(qkv + base + 2048);
    const u16x8 khi = *(const u16x8*)(qkv + base + 2048 + 64);
    u16x8 qlo_o, qhi_o, klo_o, khi_o;
#pragma unroll
    for (int j = 0; j < 8; ++j) {
      const float inv = expf((float)(d0 + j) * (-0.14391156509731588f));
      float sv, cv;
      sincosf(pos * inv, &sv, &cv);
      const float q1 = bf2f(qlo[j]), q2 = bf2f(qhi[j]);
      qlo_o[j] = f2bf(q1 * cv - q2 * sv);
      qhi_o[j] = f2bf(q2 * cv + q1 * sv);
      const float k1 = bf2f(klo[j]), k2 = bf2f(khi[j]);
      klo_o[j] = f2bf(k1 * cv - k2 * sv);
      khi_o[j] = f2bf(k2 * cv + k1 * sv);
    }
    *(u16x8*)(qkv + base) = qlo_o;
    *(u16x8*)(qkv + base + 64) = qhi_o;
    *(u16x8*)(qkv + base + 2048) = klo_o;
    *(u16x8*)(qkv + base + 2048 + 64) = khi_o;
  } else {
    // ---- V transpose (r25-exact logic) ----
    const int lin = blk - 2048;               // 0..2047
    const int b = lin >> 10, h = (lin >> 6) & 15;
    const int dht = (lin >> 5) & 1, tt = lin & 31;
    const int t0 = tt * 64, dh0 = dht * 64;
    const u16* Vb = qkv + (size_t)b * 2048 * 6144 + h * 128 + 4096 + dh0;
#pragma unroll
    for (int it = 0; it < 2; ++it) {
      const int idx = it * 256 + tid;
      const int i = idx >> 3, c = idx & 7;
      const u16x8 v = *(const u16x8*)(Vb + (size_t)(t0 + i) * 6144 + c * 8);
#pragma unroll
      for (int e = 0; e < 8; ++e) tile[c * 8 + e][i] = v[e];
    }
    __syncthreads();
    u16* dst = vT + ((size_t)(b * 16 + h) * 128 + dh0) * 2048 + t0;
#pragma unroll
    for (int it = 0; it < 2; ++it) {
      const int idx = it * 256 + tid;
      const int j = idx >> 3, ct = idx & 7;
      const u16x8 o = *(const u16x8*)&tile[j][ct * 8];
      *(u16x8*)(dst + (size_t)j * 2048 + ct * 8) = o;
    }
  }
}

// ---- Flash attention v6.1: v6 + setprio around MFMA clusters ----
__global__ __launch_bounds__(256, 2)
void attn_kernel(const u16* __restrict__ qkv, const u16* __restrict__ vT,
                 u16* __restrict__ ctx) {
  __shared__ __align__(16) u16 kbuf[2][2][32 * 128];       // 32 KB
  __shared__ __align__(16) u16 vbuf[2][128 * 64];          // 32 KB
  __shared__ __align__(16) u16 Plds[4][2][2][16 * 32];     // 16 KB [w][rg][hh]
  const int tid = threadIdx.x, lane = tid & 63, w = tid >> 6;
  const int l15 = lane & 15, l4 = lane >> 4;
  const int lin = blockIdx.x;                    // 0..511
  const int xcd = lin & 7;
  const int iw = lin >> 3;                       // 0..63
  const int bh = xcd + 8 * (iw & 3);
  const int e = iw >> 2;                         // 0..15
  const int qt = (e < 8) ? (15 - e) : (e - 8);   // pair-balanced, long first
  const int b = bh >> 4, h = bh & 15;
  const u16* Qb = qkv + (size_t)b * 2048 * 6144 + h * 128;
  const u16* Kb = Qb + 2048;
  const u16* vTb = vT + (size_t)bh * 128 * 2048;

  const int ks0 = (w * 2 + 0) * 64 + lane;
  const int ks1 = (w * 2 + 1) * 64 + lane;
  const int kr0 = ks0 >> 4, kc0 = (ks0 & 15) ^ (kr0 & 15);
  const int kr1 = ks1 >> 4, kc1 = (ks1 & 15) ^ (kr1 & 15);
  int vrow[4], vkc[4];
#pragma unroll
  for (int i = 0; i < 4; ++i) {
    const int idx = i * 256 + tid;
    vrow[i] = idx >> 3;
    vkc[i] = ((idx & 7) ^ (vrow[i] & 7)) * 8;
  }

  const float scale = 0.08838834764831845f;
  const float M0 = 12.0f;
  const f32x4 fzero = {0.f, 0.f, 0.f, 0.f};

  const int q0w = qt * 128 + w * 32;             // wave's first q row
  const int nt64 = qt * 2 + 2;                   // 64-kv tiles (uniform)

  bf16x8 qf[2][4];
#pragma unroll
  for (int rg = 0; rg < 2; ++rg)
#pragma unroll
    for (int c = 0; c < 4; ++c)
      qf[rg][c] = *(const bf16x8*)(Qb + (size_t)(q0w + rg * 16 + l15) * 6144 + c * 32 + l4 * 8);

  f32x4 o[2][8];
#pragma unroll
  for (int rg = 0; rg < 2; ++rg)
#pragma unroll
    for (int ch = 0; ch < 8; ++ch) o[rg][ch] = fzero;
  float lpart[2][4] = {{0.f, 0.f, 0.f, 0.f}, {0.f, 0.f, 0.f, 0.f}};

  // prologue: stage K64(0) and V64(0) into buffer 0
#pragma unroll
  for (int hh = 0; hh < 2; ++hh) {
    __builtin_amdgcn_global_load_lds(
        (AS1 void*)(Kb + (size_t)(hh * 32 + kr0) * 6144 + kc0 * 8),
        (AS3 void*)(&kbuf[0][hh][(w * 2 + 0) * 512]), 16, 0, 0);
    __builtin_amdgcn_global_load_lds(
        (AS1 void*)(Kb + (size_t)(hh * 32 + kr1) * 6144 + kc1 * 8),
        (AS3 void*)(&kbuf[0][hh][(w * 2 + 1) * 512]), 16, 0, 0);
  }
#pragma unroll
  for (int i = 0; i < 4; ++i)
    __builtin_amdgcn_global_load_lds(
        (AS1 void*)(vTb + (size_t)vrow[i] * 2048 + vkc[i]),
        (AS3 void*)(&vbuf[0][(i * 256 + tid) * 8]), 16, 0, 0);
  __syncthreads();  // K64(0)/V64(0) visible

  for (int t = 0; t < nt64; ++t) {
    const int cur = t & 1, nxtb = cur ^ 1;
    const int kv0 = t * 64;
    const bool has_next = (t + 1 < nt64);
    // QK: each kf ds_read feeds both row-groups
    f32x4 sv[2][4];
#pragma unroll
    for (int rg = 0; rg < 2; ++rg)
#pragma unroll
      for (int i = 0; i < 4; ++i) sv[rg][i] = fzero;
    __builtin_amdgcn_s_setprio(1);
#pragma unroll
    for (int hh = 0; hh < 2; ++hh) {
#pragma unroll
      for (int c = 0; c < 4; ++c) {
        const bf16x8 kf = *(const bf16x8*)&kbuf[cur][hh][l15 * 128 + (((c * 4 + l4) ^ l15) << 3)];
        sv[0][hh * 2] = __builtin_amdgcn_mfma_f32_16x16x32_bf16(qf[0][c], kf, sv[0][hh * 2], 0, 0, 0);
        sv[1][hh * 2] = __builtin_amdgcn_mfma_f32_16x16x32_bf16(qf[1][c], kf, sv[1][hh * 2], 0, 0, 0);
      }
#pragma unroll
      for (int c = 0; c < 4; ++c) {
        const bf16x8 kf = *(const bf16x8*)&kbuf[cur][hh][(16 + l15) * 128 + (((c * 4 + l4) ^ l15) << 3)];
        sv[0][hh * 2 + 1] = __builtin_amdgcn_mfma_f32_16x16x32_bf16(qf[0][c], kf, sv[0][hh * 2 + 1], 0, 0, 0);
        sv[1][hh * 2 + 1] = __builtin_amdgcn_mfma_f32_16x16x32_bf16(qf[1][c], kf, sv[1][hh * 2 + 1], 0, 0, 0);
      }
    }
    __builtin_amdgcn_s_setprio(0);
    if (has_next) {  // K(t+1) stage before the barrier (drain publishes it)
#pragma unroll
      for (int hh = 0; hh < 2; ++hh) {
        __builtin_amdgcn_global_load_lds(
            (AS1 void*)(Kb + (size_t)(kv0 + 64 + hh * 32 + kr0) * 6144 + kc0 * 8),
            (AS3 void*)(&kbuf[nxtb][hh][(w * 2 + 0) * 512]), 16, 0, 0);
        __builtin_amdgcn_global_load_lds(
            (AS1 void*)(Kb + (size_t)(kv0 + 64 + hh * 32 + kr1) * 6144 + kc1 * 8),
            (AS3 void*)(&kbuf[nxtb][hh][(w * 2 + 1) * 512]), 16, 0, 0);
      }
    }
    // softmax per row-group x kv-half
#pragma unroll
    for (int rg = 0; rg < 2; ++rg) {
      const int q0r = q0w + rg * 16;
#pragma unroll
      for (int hh = 0; hh < 2; ++hh) {
        const int kb0 = kv0 + hh * 32;
        if (kb0 + 31 <= q0r) {
#pragma unroll
          for (int r = 0; r < 4; ++r) {
            const float p0 = __expf(fmaf(sv[rg][hh * 2][r], scale, -M0));
            const float p1 = __expf(fmaf(sv[rg][hh * 2 + 1][r], scale, -M0));
            lpart[rg][r] += p0 + p1;
            const int row = l4 * 4 + r;
            const int g0 = ((l15 >> 3) ^ l4) & 3;
            const int g1 = (((l15 >> 3) | 2) ^ l4) & 3;
            Plds[w][rg][hh][row * 32 + g0 * 8 + (l15 & 7)] = f2bf(p0);
            Plds[w][rg][hh][row * 32 + g1 * 8 + (l15 & 7)] = f2bf(p1);
          }
        } else {
#pragma unroll
          for (int r = 0; r < 4; ++r) {
            const int qg = q0r + l4 * 4 + r;
            const float p0 = (kb0 + l15 <= qg) ? __expf(fmaf(sv[rg][hh * 2][r], scale, -M0)) : 0.f;
            const float p1 = (kb0 + 16 + l15 <= qg) ? __expf(fmaf(sv[rg][hh * 2 + 1][r], scale, -M0)) : 0.f;
            lpart[rg][r] += p0 + p1;
            const int row = l4 * 4 + r;
            const int g0 = ((l15 >> 3) ^ l4) & 3;
            const int g1 = (((l15 >> 3) | 2) ^ l4) & 3;
            Plds[w][rg][hh][row * 32 + g0 * 8 + (l15 & 7)] = f2bf(p0);
            Plds[w][rg][hh][row * 32 + g1 * 8 + (l15 & 7)] = f2bf(p1);
          }
        }
      }
    }
    __syncthreads();  // THE barrier: P visible, K(t+1)/V(t) settled
    if (has_next) {  // V(t+1) stage AFTER barrier
#pragma unroll
      for (int i = 0; i < 4; ++i)
        __builtin_amdgcn_global_load_lds(
            (AS1 void*)(vTb + (size_t)vrow[i] * 2048 + kv0 + 64 + vkc[i]),
            (AS3 void*)(&vbuf[nxtb][(i * 256 + tid) * 8]), 16, 0, 0);
    }
    // PV: vf from vbuf[cur]
    const bf16x8 pa00 = *(const bf16x8*)&Plds[w][0][0][l15 * 32 + ((l4 ^ (l15 >> 2)) << 3)];
    const bf16x8 pa01 = *(const bf16x8*)&Plds[w][0][1][l15 * 32 + ((l4 ^ (l15 >> 2)) << 3)];
    const bf16x8 pa10 = *(const bf16x8*)&Plds[w][1][0][l15 * 32 + ((l4 ^ (l15 >> 2)) << 3)];
    const bf16x8 pa11 = *(const bf16x8*)&Plds[w][1][1][l15 * 32 + ((l4 ^ (l15 >> 2)) << 3)];
    __builtin_amdgcn_s_setprio(1);
#pragma unroll
    for (int ch = 0; ch < 8; ++ch) {
      const int dh = ch * 16 + l15;
      const int c0 = ((l4 ^ (l15 & 7)) << 3);
      const int c1 = (((4 + l4) ^ (l15 & 7)) << 3);
      const bf16x8 vf0 = *(const bf16x8*)&vbuf[cur][dh * 64 + c0];
      o[0][ch] = __builtin_amdgcn_mfma_f32_16x16x32_bf16(pa00, vf0, o[0][ch], 0, 0, 0);
      o[1][ch] = __builtin_amdgcn_mfma_f32_16x16x32_bf16(pa10, vf0, o[1][ch], 0, 0, 0);
      const bf16x8 vf1 = *(const bf16x8*)&vbuf[cur][dh * 64 + c1];
      o[0][ch] = __builtin_amdgcn_mfma_f32_16x16x32_bf16(pa01, vf1, o[0][ch], 0, 0, 0);
      o[1][ch] = __builtin_amdgcn_mfma_f32_16x16x32_bf16(pa11, vf1, o[1][ch], 0, 0, 0);
    }
    __builtin_amdgcn_s_setprio(0);
  }
#pragma unroll
  for (int rg = 0; rg < 2; ++rg) {
    float invl[4];
#pragma unroll
    for (int r = 0; r < 4; ++r) {
      float l = lpart[rg][r];
      l += __shfl_xor(l, 1);
      l += __shfl_xor(l, 2);
      l += __shfl_xor(l, 4);
      l += __shfl_xor(l, 8);
      invl[r] = 1.0f / l;
    }
#pragma unroll
    for (int ch = 0; ch < 8; ++ch)
#pragma unroll
      for (int r = 0; r < 4; ++r) {
        const int gq = q0w + rg * 16 + l4 * 4 + r;
        ctx[(size_t)(b * 2048 + gq) * 2048 + h * 128 + ch * 16 + l15] =
            f2bf(o[rg][ch][r] * invl[r]);
      }
  }
}

extern "C" void kernel_launch(void* const* d_in, const int* in_sizes, int n_in,
                              void* d_out, int out_size, void* d_ws, size_t ws_size,
                              hipStream_t stream) {
  const float* x     = (const float*)d_in[0];   // (2,2048,2048) fp32
  const float* wqkv  = (const float*)d_in[1];   // (6144,2048) fp32
  const float* wproj = (const float*)d_in[2];   // (2048,2048) fp32
  const int*   soff  = (const int*)d_in[3];     // scalar int
  float* out = (float*)d_out;                   // (2,2048,2048) fp32

  u16* wsu    = (u16*)d_ws;
  u16* xb     = wsu;                    //  8388608 u16 (dead after gemm1)
  u16* wqkvb  = xb + 8388608;           // 12582912 u16 (dead after gemm1)
  u16* wprojb = wqkvb + 12582912;       //  4194304 u16
  u16* qkv    = wprojb + 4194304;       // 25165824 u16
  u16* ctx    = xb;                     // reuse xb region
  u16* vT     = wqkvb;                  // reuse wqkvb region (8388608 u16 fits)

  conv_all<<<24576, 256, 0, stream>>>(x, wqkv, wproj, wsu);

  gemm_bt<false><<<dim3(48, 32), 256, 0, stream>>>(xb, wqkvb, qkv, 4096, 6144, 2048);
  prep_kernel<<<4096, 256, 0, stream>>>(qkv, vT, soff);
  attn_kernel<<<512, 256, 0, stream>>>(qkv, vT, ctx);
  gemm_bt<true><<<dim3(16, 32), 256, 0, stream>>>(ctx, wprojb, out, 4096, 2048, 2048);
}

// Round 27
// 240.089 us; speedup vs baseline: 2.0405x; 2.0405x over previous
//
#include <hip/hip_runtime.h>
#include <math.h>

typedef __bf16 bf16x8 __attribute__((ext_vector_type(8)));
typedef float f32x4 __attribute__((ext_vector_type(4)));
typedef unsigned short u16;
typedef unsigned short u16x4 __attribute__((ext_vector_type(4)));
typedef unsigned short u16x8 __attribute__((ext_vector_type(8)));
typedef unsigned int u32;

#define AS1 __attribute__((address_space(1)))
#define AS3 __attribute__((address_space(3)))

static __device__ __forceinline__ float bf2f(u16 u) {
  union { u32 i; float f; } v; v.i = ((u32)u) << 16; return v.f;
}
// native RTNE hardware convert
static __device__ __forceinline__ u16 f2bf(float f) {
  union { __bf16 b; u16 u; } v; v.b = (__bf16)f; return v.u;
}

// ---- merged fp32 -> bf16 convert for all three inputs (dst contiguous) ----
__global__ __launch_bounds__(256)
void conv_all(const float* __restrict__ x, const float* __restrict__ wq,
              const float* __restrict__ wp, u16* __restrict__ dst) {
  const int gid = blockIdx.x * 256 + threadIdx.x;  // 0..6291455 (x4 elems)
  const float* src;
  int off;
  if (gid < 2097152) { src = x; off = gid; }
  else if (gid < 2097152 + 3145728) { src = wq; off = gid - 2097152; }
  else { src = wp; off = gid - (2097152 + 3145728); }
  const float4 v = ((const float4*)src)[off];
  u16x4 p = {f2bf(v.x), f2bf(v.y), f2bf(v.z), f2bf(v.w)};
  ((u16x4*)dst)[gid] = p;
}

// ---- GEMM 128x128, BK=64 (r19-exact, NO setprio): m97 2-barrier structure ----
template <bool CF32>
__global__ __launch_bounds__(256, 4)
void gemm_bt(const u16* __restrict__ A, const u16* __restrict__ B,
             void* __restrict__ Cp, int M, int N, int K) {
  __shared__ __align__(16) u16 As[128 * 64];   // 16 KB
  __shared__ __align__(16) u16 Bs[128 * 64];   // 16 KB
  const int tid = threadIdx.x;
  const int lane = tid & 63;
  const int wid = tid >> 6;
  const int wr = wid >> 1, wc = wid & 1;
  const int l15 = lane & 15, l4 = lane >> 4;
  const int m0 = blockIdx.y * 128, n0 = blockIdx.x * 128;

  int grow[4], gkc[4];
#pragma unroll
  for (int i = 0; i < 4; ++i) {
    const int idx = i * 256 + tid;
    grow[i] = idx >> 3;
    gkc[i] = ((idx & 7) ^ (grow[i] & 7)) * 8;
  }

  const f32x4 fzero = {0.f, 0.f, 0.f, 0.f};
  f32x4 acc[4][4];
#pragma unroll
  for (int i = 0; i < 4; ++i)
#pragma unroll
    for (int j = 0; j < 4; ++j) acc[i][j] = fzero;

  for (int kt = 0; kt < K; kt += 64) {
#pragma unroll
    for (int i = 0; i < 4; ++i) {
      __builtin_amdgcn_global_load_lds(
          (AS1 void*)(A + (size_t)(m0 + grow[i]) * K + kt + gkc[i]),
          (AS3 void*)(As + (size_t)(i * 256 + tid) * 8), 16, 0, 0);
      __builtin_amdgcn_global_load_lds(
          (AS1 void*)(B + (size_t)(n0 + grow[i]) * K + kt + gkc[i]),
          (AS3 void*)(Bs + (size_t)(i * 256 + tid) * 8), 16, 0, 0);
    }
    __syncthreads();
    bf16x8 af[4][2], bfr[4][2];
#pragma unroll
    for (int m = 0; m < 4; ++m) {
      const int ra = wr * 64 + m * 16 + l15;
#pragma unroll
      for (int ks = 0; ks < 2; ++ks)
        af[m][ks] = *(const bf16x8*)&As[ra * 64 + (((ks * 4 + l4) ^ (ra & 7)) << 3)];
    }
#pragma unroll
    for (int n = 0; n < 4; ++n) {
      const int rb = wc * 64 + n * 16 + l15;
#pragma unroll
      for (int ks = 0; ks < 2; ++ks)
        bfr[n][ks] = *(const bf16x8*)&Bs[rb * 64 + (((ks * 4 + l4) ^ (rb & 7)) << 3)];
    }
#pragma unroll
    for (int m = 0; m < 4; ++m)
#pragma unroll
      for (int n = 0; n < 4; ++n) {
        acc[m][n] = __builtin_amdgcn_mfma_f32_16x16x32_bf16(af[m][0], bfr[n][0], acc[m][n], 0, 0, 0);
        acc[m][n] = __builtin_amdgcn_mfma_f32_16x16x32_bf16(af[m][1], bfr[n][1], acc[m][n], 0, 0, 0);
      }
    __syncthreads();
  }

#pragma unroll
  for (int m = 0; m < 4; ++m)
#pragma unroll
    for (int r = 0; r < 4; ++r) {
      const int gm = m0 + wr * 64 + m * 16 + l4 * 4 + r;
      if constexpr (CF32) {
        float* crow = (float*)Cp + (size_t)gm * N + n0 + wc * 64 + l15;
#pragma unroll
        for (int n = 0; n < 4; ++n) crow[n * 16] = acc[m][n][r];
      } else {
        u16* crow = (u16*)Cp + (size_t)gm * N + n0 + wc * 64 + l15;
#pragma unroll
        for (int n = 0; n < 4; ++n) crow[n * 16] = f2bf(acc[m][n][r]);
      }
    }
}

// ---- prep: RoPE on Q,K (blocks 0..2047) + V transpose (blocks 2048..4095) ----
// The two halves touch disjoint regions of qkv (Q,K vs V) -> independent.
__global__ __launch_bounds__(256)
void prep_kernel(u16* __restrict__ qkv, u16* __restrict__ vT,
                 const int* __restrict__ seq_off) {
  __shared__ __align__(16) u16 tile[64][72];
  const int blk = blockIdx.x;
  const int tid = threadIdx.x;
  if (blk < 2048) {
    // ---- RoPE (r19-exact logic) ----
    const int idx = blk * 256 + tid;
    const int d8 = idx & 7;
    const int h = (idx >> 3) & 15;
    const int t = (idx >> 7) & 2047;
    const int b = idx >> 18;
    const int d0 = d8 * 8;
    const float pos = (float)(seq_off[0] + t);
    const size_t base = ((size_t)(b * 2048 + t)) * 6144 + h * 128 + d0;
    const u16x8 qlo = *(const u16x8*)(qkv + base);
    const u16x8 qhi = *(const u16x8*)(qkv + base + 64);
    const u16x8 klo = *(const u16x8*)(qkv + base + 2048);
    const u16x8 khi = *(const u16x8*)(qkv + base + 2048 + 64);
    u16x8 qlo_o, qhi_o, klo_o, khi_o;
#pragma unroll
    for (int j = 0; j < 8; ++j) {
      const float inv = expf((float)(d0 + j) * (-0.14391156509731588f));
      float sv, cv;
      sincosf(pos * inv, &sv, &cv);
      const float q1 = bf2f(qlo[j]), q2 = bf2f(qhi[j]);
      qlo_o[j] = f2bf(q1 * cv - q2 * sv);
      qhi_o[j] = f2bf(q2 * cv + q1 * sv);
      const float k1 = bf2f(klo[j]), k2 = bf2f(khi[j]);
      klo_o[j] = f2bf(k1 * cv - k2 * sv);
      khi_o[j] = f2bf(k2 * cv + k1 * sv);
    }
    *(u16x8*)(qkv + base) = qlo_o;
    *(u16x8*)(qkv + base + 64) = qhi_o;
    *(u16x8*)(qkv + base + 2048) = klo_o;
    *(u16x8*)(qkv + base + 2048 + 64) = khi_o;
  } else {
    // ---- V transpose (r25-exact logic) ----
    const int lin = blk - 2048;               // 0..2047
    const int b = lin >> 10, h = (lin >> 6) & 15;
    const int dht = (lin >> 5) & 1, tt = lin & 31;
    const int t0 = tt * 64, dh0 = dht * 64;
    const u16* Vb = qkv + (size_t)b * 2048 * 6144 + h * 128 + 4096 + dh0;
#pragma unroll
    for (int it = 0; it < 2; ++it) {
      const int idx = it * 256 + tid;
      const int i = idx >> 3, c = idx & 7;
      const u16x8 v = *(const u16x8*)(Vb + (size_t)(t0 + i) * 6144 + c * 8);
#pragma unroll
      for (int e = 0; e < 8; ++e) tile[c * 8 + e][i] = v[e];
    }
    __syncthreads();
    u16* dst = vT + ((size_t)(b * 16 + h) * 128 + dh0) * 2048 + t0;
#pragma unroll
    for (int it = 0; it < 2; ++it) {
      const int idx = it * 256 + tid;
      const int j = idx >> 3, ct = idx & 7;
      const u16x8 o = *(const u16x8*)&tile[j][ct * 8];
      *(u16x8*)(dst + (size_t)j * 2048 + ct * 8) = o;
    }
  }
}

// ---- Flash attention v6 (r25-exact, NO setprio) ----
__global__ __launch_bounds__(256, 2)
void attn_kernel(const u16* __restrict__ qkv, const u16* __restrict__ vT,
                 u16* __restrict__ ctx) {
  __shared__ __align__(16) u16 kbuf[2][2][32 * 128];       // 32 KB
  __shared__ __align__(16) u16 vbuf[2][128 * 64];          // 32 KB
  __shared__ __align__(16) u16 Plds[4][2][2][16 * 32];     // 16 KB [w][rg][hh]
  const int tid = threadIdx.x, lane = tid & 63, w = tid >> 6;
  const int l15 = lane & 15, l4 = lane >> 4;
  const int lin = blockIdx.x;                    // 0..511
  const int xcd = lin & 7;
  const int iw = lin >> 3;                       // 0..63
  const int bh = xcd + 8 * (iw & 3);
  const int e = iw >> 2;                         // 0..15
  const int qt = (e < 8) ? (15 - e) : (e - 8);   // pair-balanced, long first
  const int b = bh >> 4, h = bh & 15;
  const u16* Qb = qkv + (size_t)b * 2048 * 6144 + h * 128;
  const u16* Kb = Qb + 2048;
  const u16* vTb = vT + (size_t)bh * 128 * 2048;

  const int ks0 = (w * 2 + 0) * 64 + lane;
  const int ks1 = (w * 2 + 1) * 64 + lane;
  const int kr0 = ks0 >> 4, kc0 = (ks0 & 15) ^ (kr0 & 15);
  const int kr1 = ks1 >> 4, kc1 = (ks1 & 15) ^ (kr1 & 15);
  int vrow[4], vkc[4];
#pragma unroll
  for (int i = 0; i < 4; ++i) {
    const int idx = i * 256 + tid;
    vrow[i] = idx >> 3;
    vkc[i] = ((idx & 7) ^ (vrow[i] & 7)) * 8;
  }

  const float scale = 0.08838834764831845f;
  const float M0 = 12.0f;
  const f32x4 fzero = {0.f, 0.f, 0.f, 0.f};

  const int q0w = qt * 128 + w * 32;             // wave's first q row
  const int nt64 = qt * 2 + 2;                   // 64-kv tiles (uniform)

  bf16x8 qf[2][4];
#pragma unroll
  for (int rg = 0; rg < 2; ++rg)
#pragma unroll
    for (int c = 0; c < 4; ++c)
      qf[rg][c] = *(const bf16x8*)(Qb + (size_t)(q0w + rg * 16 + l15) * 6144 + c * 32 + l4 * 8);

  f32x4 o[2][8];
#pragma unroll
  for (int rg = 0; rg < 2; ++rg)
#pragma unroll
    for (int ch = 0; ch < 8; ++ch) o[rg][ch] = fzero;
  float lpart[2][4] = {{0.f, 0.f, 0.f, 0.f}, {0.f, 0.f, 0.f, 0.f}};

  // prologue: stage K64(0) and V64(0) into buffer 0
#pragma unroll
  for (int hh = 0; hh < 2; ++hh) {
    __builtin_amdgcn_global_load_lds(
        (AS1 void*)(Kb + (size_t)(hh * 32 + kr0) * 6144 + kc0 * 8),
        (AS3 void*)(&kbuf[0][hh][(w * 2 + 0) * 512]), 16, 0, 0);
    __builtin_amdgcn_global_load_lds(
        (AS1 void*)(Kb + (size_t)(hh * 32 + kr1) * 6144 + kc1 * 8),
        (AS3 void*)(&kbuf[0][hh][(w * 2 + 1) * 512]), 16, 0, 0);
  }
#pragma unroll
  for (int i = 0; i < 4; ++i)
    __builtin_amdgcn_global_load_lds(
        (AS1 void*)(vTb + (size_t)vrow[i] * 2048 + vkc[i]),
        (AS3 void*)(&vbuf[0][(i * 256 + tid) * 8]), 16, 0, 0);
  __syncthreads();  // K64(0)/V64(0) visible

  for (int t = 0; t < nt64; ++t) {
    const int cur = t & 1, nxtb = cur ^ 1;
    const int kv0 = t * 64;
    const bool has_next = (t + 1 < nt64);
    // QK: each kf ds_read feeds both row-groups
    f32x4 sv[2][4];
#pragma unroll
    for (int rg = 0; rg < 2; ++rg)
#pragma unroll
      for (int i = 0; i < 4; ++i) sv[rg][i] = fzero;
#pragma unroll
    for (int hh = 0; hh < 2; ++hh) {
#pragma unroll
      for (int c = 0; c < 4; ++c) {
        const bf16x8 kf = *(const bf16x8*)&kbuf[cur][hh][l15 * 128 + (((c * 4 + l4) ^ l15) << 3)];
        sv[0][hh * 2] = __builtin_amdgcn_mfma_f32_16x16x32_bf16(qf[0][c], kf, sv[0][hh * 2], 0, 0, 0);
        sv[1][hh * 2] = __builtin_amdgcn_mfma_f32_16x16x32_bf16(qf[1][c], kf, sv[1][hh * 2], 0, 0, 0);
      }
#pragma unroll
      for (int c = 0; c < 4; ++c) {
        const bf16x8 kf = *(const bf16x8*)&kbuf[cur][hh][(16 + l15) * 128 + (((c * 4 + l4) ^ l15) << 3)];
        sv[0][hh * 2 + 1] = __builtin_amdgcn_mfma_f32_16x16x32_bf16(qf[0][c], kf, sv[0][hh * 2 + 1], 0, 0, 0);
        sv[1][hh * 2 + 1] = __builtin_amdgcn_mfma_f32_16x16x32_bf16(qf[1][c], kf, sv[1][hh * 2 + 1], 0, 0, 0);
      }
    }
    if (has_next) {  // K(t+1) stage before the barrier (drain publishes it)
#pragma unroll
      for (int hh = 0; hh < 2; ++hh) {
        __builtin_amdgcn_global_load_lds(
            (AS1 void*)(Kb + (size_t)(kv0 + 64 + hh * 32 + kr0) * 6144 + kc0 * 8),
            (AS3 void*)(&kbuf[nxtb][hh][(w * 2 + 0) * 512]), 16, 0, 0);
        __builtin_amdgcn_global_load_lds(
            (AS1 void*)(Kb + (size_t)(kv0 + 64 + hh * 32 + kr1) * 6144 + kc1 * 8),
            (AS3 void*)(&kbuf[nxtb][hh][(w * 2 + 1) * 512]), 16, 0, 0);
      }
    }
    // softmax per row-group x kv-half
#pragma unroll
    for (int rg = 0; rg < 2; ++rg) {
      const int q0r = q0w + rg * 16;
#pragma unroll
      for (int hh = 0; hh < 2; ++hh) {
        const int kb0 = kv0 + hh * 32;
        if (kb0 + 31 <= q0r) {
#pragma unroll
          for (int r = 0; r < 4; ++r) {
            const float p0 = __expf(fmaf(sv[rg][hh * 2][r], scale, -M0));
            const float p1 = __expf(fmaf(sv[rg][hh * 2 + 1][r], scale, -M0));
            lpart[rg][r] += p0 + p1;
            const int row = l4 * 4 + r;
            const int g0 = ((l15 >> 3) ^ l4) & 3;
            const int g1 = (((l15 >> 3) | 2) ^ l4) & 3;
            Plds[w][rg][hh][row * 32 + g0 * 8 + (l15 & 7)] = f2bf(p0);
            Plds[w][rg][hh][row * 32 + g1 * 8 + (l15 & 7)] = f2bf(p1);
          }
        } else {
#pragma unroll
          for (int r = 0; r < 4; ++r) {
            const int qg = q0r + l4 * 4 + r;
            const float p0 = (kb0 + l15 <= qg) ? __expf(fmaf(sv[rg][hh * 2][r], scale, -M0)) : 0.f;
            const float p1 = (kb0 + 16 + l15 <= qg) ? __expf(fmaf(sv[rg][hh * 2 + 1][r], scale, -M0)) : 0.f;
            lpart[rg][r] += p0 + p1;
            const int row = l4 * 4 + r;
            const int g0 = ((l15 >> 3) ^ l4) & 3;
            const int g1 = (((l15 >> 3) | 2) ^ l4) & 3;
            Plds[w][rg][hh][row * 32 + g0 * 8 + (l15 & 7)] = f2bf(p0);
            Plds[w][rg][hh][row * 32 + g1 * 8 + (l15 & 7)] = f2bf(p1);
          }
        }
      }
    }
    __syncthreads();  // THE barrier: P visible, K(t+1)/V(t) settled
    if (has_next) {  // V(t+1) stage AFTER barrier
#pragma unroll
      for (int i = 0; i < 4; ++i)
        __builtin_amdgcn_global_load_lds(
            (AS1 void*)(vTb + (size_t)vrow[i] * 2048 + kv0 + 64 + vkc[i]),
            (AS3 void*)(&vbuf[nxtb][(i * 256 + tid) * 8]), 16, 0, 0);
    }
    // PV: vf from vbuf[cur]
    const bf16x8 pa00 = *(const bf16x8*)&Plds[w][0][0][l15 * 32 + ((l4 ^ (l15 >> 2)) << 3)];
    const bf16x8 pa01 = *(const bf16x8*)&Plds[w][0][1][l15 * 32 + ((l4 ^ (l15 >> 2)) << 3)];
    const bf16x8 pa10 = *(const bf16x8*)&Plds[w][1][0][l15 * 32 + ((l4 ^ (l15 >> 2)) << 3)];
    const bf16x8 pa11 = *(const bf16x8*)&Plds[w][1][1][l15 * 32 + ((l4 ^ (l15 >> 2)) << 3)];
#pragma unroll
    for (int ch = 0; ch < 8; ++ch) {
      const int dh = ch * 16 + l15;
      const int c0 = ((l4 ^ (l15 & 7)) << 3);
      const int c1 = (((4 + l4) ^ (l15 & 7)) << 3);
      const bf16x8 vf0 = *(const bf16x8*)&vbuf[cur][dh * 64 + c0];
      o[0][ch] = __builtin_amdgcn_mfma_f32_16x16x32_bf16(pa00, vf0, o[0][ch], 0, 0, 0);
      o[1][ch] = __builtin_amdgcn_mfma_f32_16x16x32_bf16(pa10, vf0, o[1][ch], 0, 0, 0);
      const bf16x8 vf1 = *(const bf16x8*)&vbuf[cur][dh * 64 + c1];
      o[0][ch] = __builtin_amdgcn_mfma_f32_16x16x32_bf16(pa01, vf1, o[0][ch], 0, 0, 0);
      o[1][ch] = __builtin_amdgcn_mfma_f32_16x16x32_bf16(pa11, vf1, o[1][ch], 0, 0, 0);
    }
  }
#pragma unroll
  for (int rg = 0; rg < 2; ++rg) {
    float invl[4];
#pragma unroll
    for (int r = 0; r < 4; ++r) {
      float l = lpart[rg][r];
      l += __shfl_xor(l, 1);
      l += __shfl_xor(l, 2);
      l += __shfl_xor(l, 4);
      l += __shfl_xor(l, 8);
      invl[r] = 1.0f / l;
    }
#pragma unroll
    for (int ch = 0; ch < 8; ++ch)
#pragma unroll
      for (int r = 0; r < 4; ++r) {
        const int gq = q0w + rg * 16 + l4 * 4 + r;
        ctx[(size_t)(b * 2048 + gq) * 2048 + h * 128 + ch * 16 + l15] =
            f2bf(o[rg][ch][r] * invl[r]);
      }
  }
}

extern "C" void kernel_launch(void* const* d_in, const int* in_sizes, int n_in,
                              void* d_out, int out_size, void* d_ws, size_t ws_size,
                              hipStream_t stream) {
  const float* x     = (const float*)d_in[0];   // (2,2048,2048) fp32
  const float* wqkv  = (const float*)d_in[1];   // (6144,2048) fp32
  const float* wproj = (const float*)d_in[2];   // (2048,2048) fp32
  const int*   soff  = (const int*)d_in[3];     // scalar int
  float* out = (float*)d_out;                   // (2,2048,2048) fp32

  u16* wsu    = (u16*)d_ws;
  u16* xb     = wsu;                    //  8388608 u16 (dead after gemm1)
  u16* wqkvb  = xb + 8388608;           // 12582912 u16 (dead after gemm1)
  u16* wprojb = wqkvb + 12582912;       //  4194304 u16
  u16* qkv    = wprojb + 4194304;       // 25165824 u16
  u16* ctx    = xb;                     // reuse xb region
  u16* vT     = wqkvb;                  // reuse wqkvb region (8388608 u16 fits)

  conv_all<<<24576, 256, 0, stream>>>(x, wqkv, wproj, wsu);

  gemm_bt<false><<<dim3(48, 32), 256, 0, stream>>>(xb, wqkvb, qkv, 4096, 6144, 2048);
  prep_kernel<<<4096, 256, 0, stream>>>(qkv, vT, soff);
  attn_kernel<<<512, 256, 0, stream>>>(qkv, vT, ctx);
  gemm_bt<true><<<dim3(16, 32), 256, 0, stream>>>(ctx, wprojb, out, 4096, 2048, 2048);
}